// Round 6
// baseline (860.725 us; speedup 1.0000x reference)
//
#include <hip/hip_runtime.h>

#define N_NODES 50000
#define N_EDGES 800000
#define DIM 128
#define NB 49   // ceil(N_NODES / 1024)

typedef int   vint4   __attribute__((ext_vector_type(4)));
typedef float vfloat4 __attribute__((ext_vector_type(4)));
typedef unsigned int vuint2 __attribute__((ext_vector_type(2)));

struct IdxPtrs8 { const int* p[8]; };
struct SrcDst4  { const int* s[4]; const int* d[4]; };
struct FeatPtrs { const float* f[4]; };
struct GemmArgs { const float* W[4]; const float* b[4]; };

// ---------------------------------------------------------------------------
// 1) degree histogram for all 8 index arrays: blockIdx.y selects the array.
// ---------------------------------------------------------------------------
__global__ __launch_bounds__(256) void count_all(IdxPtrs8 idx, int* __restrict__ deg) {
    const int a = blockIdx.y;
    const int* __restrict__ x = idx.p[a];
    int* cnt = deg + (size_t)a * N_NODES;
    int i = blockIdx.x * 256 + threadIdx.x;
    if (i < N_EDGES / 4) {
        vint4 v = __builtin_nontemporal_load((const vint4*)x + i);
        atomicAdd(&cnt[v.x], 1);
        atomicAdd(&cnt[v.y], 1);
        atomicAdd(&cnt[v.z], 1);
        atomicAdd(&cnt[v.w], 1);
    }
}

// ---------------------------------------------------------------------------
// 2) multi-block scan of dst-degrees -> CSR offsets + cursors.
//    scan_write also converts the dst-degree slot to rinv (float) in place.
// ---------------------------------------------------------------------------
__global__ __launch_bounds__(256) void scan_partial(const int* __restrict__ deg,
                                                    int* __restrict__ part) {
    const int r = blockIdx.y;
    const int* cnt = deg + (size_t)(2 * r + 1) * N_NODES;
    __shared__ int red[256];
    const int tid = threadIdx.x;
    int lo = blockIdx.x * 1024 + tid * 4;
    int s = 0;
#pragma unroll
    for (int j = 0; j < 4; j++) {
        int i = lo + j;
        if (i < N_NODES) s += cnt[i];
    }
    red[tid] = s;
    __syncthreads();
    for (int d = 128; d > 0; d >>= 1) {
        if (tid < d) red[tid] += red[tid + d];
        __syncthreads();
    }
    if (tid == 0) part[r * NB + blockIdx.x] = red[0];
}

__global__ __launch_bounds__(256) void scan_base(int* __restrict__ part) {
    __shared__ int l[4 * NB];
    const int t = threadIdx.x;
    if (t < 4 * NB) l[t] = part[t];
    __syncthreads();
    if (t < 4) {
        int run = 0;
        for (int b = 0; b < NB; b++) {
            int v = l[t * NB + b];
            l[t * NB + b] = run;
            run += v;
        }
    }
    __syncthreads();
    if (t < 4 * NB) part[t] = l[t];
}

__global__ __launch_bounds__(256) void scan_write(int* __restrict__ deg,
                                                  const int* __restrict__ part,
                                                  int* __restrict__ offs,
                                                  int* __restrict__ cursor) {
    const int r = blockIdx.y;
    int* cnt = deg + (size_t)(2 * r + 1) * N_NODES;   // dst-degree slot
    int* off = offs + (size_t)r * (N_NODES + 1);
    int* cur = cursor + (size_t)r * N_NODES;
    __shared__ int sums[256];
    const int tid = threadIdx.x;
    int lo = blockIdx.x * 1024 + tid * 4;
    int c[4];
    int s = 0;
#pragma unroll
    for (int j = 0; j < 4; j++) {
        int i = lo + j;
        c[j] = (i < N_NODES) ? cnt[i] : 0;
        s += c[j];
    }
    sums[tid] = s;
    __syncthreads();
    for (int d = 1; d < 256; d <<= 1) {
        int v = (tid >= d) ? sums[tid - d] : 0;
        __syncthreads();
        sums[tid] += v;
        __syncthreads();
    }
    int run = part[r * NB + blockIdx.x] + sums[tid] - s;
#pragma unroll
    for (int j = 0; j < 4; j++) {
        int i = lo + j;
        if (i < N_NODES) {
            off[i] = run;
            cur[i] = run;
            run += c[j];
            // in-place: dst-degree -> rinv_dst (location owned by this thread)
            ((float*)cnt)[i] = rsqrtf((float)(c[j] < 1 ? 1 : c[j]));
        }
    }
    if (blockIdx.x == 0 && tid == 0) off[N_NODES] = N_EDGES;
}

// ---------------------------------------------------------------------------
// 3) CSR fill: 16 edges per thread (4x int4) for deep atomic MLP; csr writes
//    nontemporal (scattered 4B, written once, read once much later).
// ---------------------------------------------------------------------------
__global__ __launch_bounds__(256) void fill_all(SrcDst4 sd, int* __restrict__ cursor,
                                                int* __restrict__ csr) {
    const int r = blockIdx.y;
    const int* __restrict__ src = sd.s[r];
    const int* __restrict__ dst = sd.d[r];
    int* cur = cursor + (size_t)r * N_NODES;
    int* out = csr + (size_t)r * N_EDGES;
    const int b0 = blockIdx.x * 1024;      // int4 index base for this block
#pragma unroll
    for (int c = 0; c < 4; c++) {
        int i4 = b0 + c * 256 + threadIdx.x;
        if (i4 < N_EDGES / 4) {
            vint4 s = __builtin_nontemporal_load((const vint4*)src + i4);
            vint4 d = __builtin_nontemporal_load((const vint4*)dst + i4);
            int p0 = atomicAdd(&cur[d.x], 1);
            int p1 = atomicAdd(&cur[d.y], 1);
            int p2 = atomicAdd(&cur[d.z], 1);
            int p3 = atomicAdd(&cur[d.w], 1);
            __builtin_nontemporal_store(s.x, &out[p0]);
            __builtin_nontemporal_store(s.y, &out[p1]);
            __builtin_nontemporal_store(s.z, &out[p2]);
            __builtin_nontemporal_store(s.w, &out[p3]);
        }
    }
}

// ---------------------------------------------------------------------------
// 4) fp32 -> bf16 feature conversion with rinv_src folded in (each feature
//    table feeds exactly one relation). Packing: uint j = elems {2j, 2j+1}.
// ---------------------------------------------------------------------------
__device__ inline unsigned f2bf(float x) {
    unsigned u = __float_as_uint(x);
    return (u + 0x7fffu + ((u >> 16) & 1u)) >> 16;
}

__global__ __launch_bounds__(256) void to_bf16(FeatPtrs fp, const int* __restrict__ deg,
                                               unsigned short* __restrict__ bf) {
    const int y = blockIdx.y;
    const float* __restrict__ f = fp.f[y];
    const int* __restrict__ dsrc = deg + (size_t)(2 * y) * N_NODES;  // src-degree (int)
    uint4* __restrict__ o = (uint4*)(bf + (size_t)y * N_NODES * DIM);
    int i = blockIdx.x * 256 + threadIdx.x;          // 8 elems per thread
    if (i * 8 + 7 < N_NODES * DIM) {
        int node = i >> 4;                           // 16 threads per 128-row
        int c = dsrc[node];
        float sc = rsqrtf((float)(c < 1 ? 1 : c));
        vfloat4 v0 = __builtin_nontemporal_load((const vfloat4*)f + i * 2);
        vfloat4 v1 = __builtin_nontemporal_load((const vfloat4*)f + i * 2 + 1);
        uint4 p;
        p.x = (f2bf(v0.y * sc) << 16) | f2bf(v0.x * sc);
        p.y = (f2bf(v0.w * sc) << 16) | f2bf(v0.z * sc);
        p.z = (f2bf(v1.y * sc) << 16) | f2bf(v1.x * sc);
        p.w = (f2bf(v1.w * sc) << 16) | f2bf(v1.z * sc);
        o[i] = p;
    }
}

// ---------------------------------------------------------------------------
// 5) gather, pre-scaled bf16 features: one wave64 per dst node; 32 lanes per
//    edge row (8 B/lane), two edges per wave (sub = lane>>5), 2-deep unroll.
// ---------------------------------------------------------------------------
__global__ __launch_bounds__(256) void gather_bf16(
    const unsigned short* __restrict__ bf, const float* __restrict__ rinv,
    const int* __restrict__ csr_all, const int* __restrict__ offs_all,
    float* __restrict__ out_base)
{
    const int r = blockIdx.y;
    const unsigned short* __restrict__ feat = bf + (size_t)r * N_NODES * DIM;
    const float* __restrict__ rinv_dst = rinv + (size_t)(2 * r + 1) * N_NODES;
    const int* __restrict__ csr = csr_all + (size_t)r * N_EDGES;
    const int* __restrict__ offs = offs_all + (size_t)r * (N_NODES + 1);
    float* out = out_base + (size_t)r * N_NODES * DIM;

    const int node = blockIdx.x * 4 + (threadIdx.x >> 6);
    if (node >= N_NODES) return;
    const int lane = threadIdx.x & 63;
    const int sub = lane >> 5;
    const int l = lane & 31;
    const int beg = offs[node];
    const int end = offs[node + 1];
    const vuint2* __restrict__ feat2 = (const vuint2*)feat;

    float acc0 = 0.f, acc1 = 0.f, acc2 = 0.f, acc3 = 0.f;
    int i = beg + sub;
    for (; i + 2 < end; i += 4) {
        int s0 = __builtin_nontemporal_load(&csr[i]);
        int s1 = __builtin_nontemporal_load(&csr[i + 2]);
        vuint2 q0 = feat2[(size_t)s0 * 32 + l];
        vuint2 q1 = feat2[(size_t)s1 * 32 + l];
        acc0 += __uint_as_float(q0.x << 16);
        acc1 += __uint_as_float(q0.x & 0xffff0000u);
        acc2 += __uint_as_float(q0.y << 16);
        acc3 += __uint_as_float(q0.y & 0xffff0000u);
        acc0 += __uint_as_float(q1.x << 16);
        acc1 += __uint_as_float(q1.x & 0xffff0000u);
        acc2 += __uint_as_float(q1.y << 16);
        acc3 += __uint_as_float(q1.y & 0xffff0000u);
    }
    if (i < end) {
        int s0 = __builtin_nontemporal_load(&csr[i]);
        vuint2 q0 = feat2[(size_t)s0 * 32 + l];
        acc0 += __uint_as_float(q0.x << 16);
        acc1 += __uint_as_float(q0.x & 0xffff0000u);
        acc2 += __uint_as_float(q0.y << 16);
        acc3 += __uint_as_float(q0.y & 0xffff0000u);
    }
    acc0 += __shfl_xor(acc0, 32);
    acc1 += __shfl_xor(acc1, 32);
    acc2 += __shfl_xor(acc2, 32);
    acc3 += __shfl_xor(acc3, 32);
    if (sub == 0) {
        float rd = rinv_dst[node];
        vfloat4 o = {acc0 * rd, acc1 * rd, acc2 * rd, acc3 * rd};
        __builtin_nontemporal_store(o, (vfloat4*)out + (size_t)node * 32 + l);
    }
}

// 5b) fp32 fallback gather (only if ws too small for bf16 tables)
__global__ __launch_bounds__(256) void gather_f32(
    FeatPtrs feats, const int* __restrict__ deg,
    const int* __restrict__ csr_all, const int* __restrict__ offs_all,
    float* __restrict__ out_base)
{
    const int r = blockIdx.y;
    const float* __restrict__ feat = feats.f[r];
    const int* __restrict__ deg_src = deg + (size_t)(2 * r) * N_NODES;      // int
    const float* __restrict__ rinv_dst = (const float*)deg + (size_t)(2 * r + 1) * N_NODES;
    const int* __restrict__ csr = csr_all + (size_t)r * N_EDGES;
    const int* __restrict__ offs = offs_all + (size_t)r * (N_NODES + 1);
    float* out = out_base + (size_t)r * N_NODES * DIM;

    const int node = blockIdx.x * 4 + (threadIdx.x >> 6);
    if (node >= N_NODES) return;
    const int lane = threadIdx.x & 63;
    const int sub = lane >> 5;
    const int l = lane & 31;
    const int beg = offs[node];
    const int end = offs[node + 1];
    const float4* __restrict__ feat4 = (const float4*)feat;

    float4 acc = make_float4(0.f, 0.f, 0.f, 0.f);
    for (int i = beg + sub; i < end; i += 2) {
        int s0 = csr[i];
        int c = deg_src[s0];
        float sc0 = rsqrtf((float)(c < 1 ? 1 : c));
        float4 v0 = feat4[(size_t)s0 * 32 + l];
        acc.x = fmaf(v0.x, sc0, acc.x); acc.y = fmaf(v0.y, sc0, acc.y);
        acc.z = fmaf(v0.z, sc0, acc.z); acc.w = fmaf(v0.w, sc0, acc.w);
    }
    acc.x += __shfl_xor(acc.x, 32);
    acc.y += __shfl_xor(acc.y, 32);
    acc.z += __shfl_xor(acc.z, 32);
    acc.w += __shfl_xor(acc.w, 32);
    if (sub == 0) {
        float rd = rinv_dst[node];
        ((float4*)out)[(size_t)node * 32 + l] =
            make_float4(acc.x * rd, acc.y * rd, acc.z * rd, acc.w * rd);
    }
}

// ---------------------------------------------------------------------------
// 6) GEMM for all outputs in one launch. blockIdx.y:
//      0: user = slot0@W0 + b0 + slot1@W1 + b1 -> slot0 AND slot1
//      1: out_d1 = slot2@W2 + b2 -> slot2 (in place)
//      2: out_d2 = slot3@W3 + b3 -> slot3 (in place)
// ---------------------------------------------------------------------------
__global__ __launch_bounds__(256) void gemm_all(GemmArgs ga, float* __restrict__ base) {
    __shared__ float Ws[128 * 128];
    __shared__ float xs[32 * 128];
    const int y = blockIdx.y;
    const int tid = threadIdx.x;
    const int row0 = blockIdx.x * 32;
    const int cg = tid & 31;
    const int rg = tid >> 5;

    float* slot0 = base;
    float* slot1 = base + (size_t)N_NODES * DIM;

    const float* aggA = (y == 0) ? slot0 : base + (size_t)(y + 1) * N_NODES * DIM;
    const float* aggB = (y == 0) ? slot1 : nullptr;
    const float* WA = (y == 0) ? ga.W[0] : ga.W[y + 1];
    const float* bA = (y == 0) ? ga.b[0] : ga.b[y + 1];
    const float* WB = ga.W[1];
    const float* bB = ga.b[1];
    float* outA = (float*)aggA;
    float* outB = (y == 0) ? slot1 : nullptr;

    float acc[4][4];
#pragma unroll
    for (int r = 0; r < 4; r++)
#pragma unroll
        for (int j = 0; j < 4; j++) acc[r][j] = 0.f;

    for (int pass = 0; pass < 2; ++pass) {
        const float* agg = pass ? aggB : aggA;
        const float* W   = pass ? WB   : WA;
        const float* b   = pass ? bB   : bA;
        if (agg == nullptr) break;
        if (pass) __syncthreads();

#pragma unroll
        for (int i = 0; i < 16; i++) {
            int f4 = tid + i * 256;
            ((float4*)Ws)[f4] = ((const float4*)W)[f4];
        }
#pragma unroll
        for (int i = 0; i < 4; i++) {
            int f4 = tid + i * 256;
            int row = row0 + (f4 >> 5);
            float4 v = make_float4(0.f, 0.f, 0.f, 0.f);
            if (row < N_NODES) v = ((const float4*)agg)[(size_t)row * 32 + (f4 & 31)];
            ((float4*)xs)[f4] = v;
        }
        __syncthreads();

        float4 bb = ((const float4*)b)[cg];
#pragma unroll
        for (int r = 0; r < 4; r++) {
            acc[r][0] += bb.x; acc[r][1] += bb.y; acc[r][2] += bb.z; acc[r][3] += bb.w;
        }

        const float4* Ws4 = (const float4*)Ws;
        const float4* xs4 = (const float4*)xs;
#pragma unroll 4
        for (int k4 = 0; k4 < 32; k4++) {
            float4 w0 = Ws4[(4 * k4 + 0) * 32 + cg];
            float4 w1 = Ws4[(4 * k4 + 1) * 32 + cg];
            float4 w2 = Ws4[(4 * k4 + 2) * 32 + cg];
            float4 w3 = Ws4[(4 * k4 + 3) * 32 + cg];
#pragma unroll
            for (int rr = 0; rr < 4; rr++) {
                float4 x = xs4[(rg + rr * 8) * 32 + k4];
                acc[rr][0] += x.x * w0.x + x.y * w1.x + x.z * w2.x + x.w * w3.x;
                acc[rr][1] += x.x * w0.y + x.y * w1.y + x.z * w2.y + x.w * w3.y;
                acc[rr][2] += x.x * w0.z + x.y * w1.z + x.z * w2.z + x.w * w3.z;
                acc[rr][3] += x.x * w0.w + x.y * w1.w + x.z * w2.w + x.w * w3.w;
            }
        }
    }

#pragma unroll
    for (int r = 0; r < 4; r++) {
        int row = row0 + rg + r * 8;
        if (row >= N_NODES) continue;
        float4 o = make_float4(acc[r][0], acc[r][1], acc[r][2], acc[r][3]);
        ((float4*)outA)[(size_t)row * 32 + cg] = o;
        if (outB) ((float4*)outB)[(size_t)row * 32 + cg] = o;
    }
}

// ---------------------------------------------------------------------------
extern "C" void kernel_launch(void* const* d_in, const int* in_sizes, int n_in,
                              void* d_out, int out_size, void* d_ws, size_t ws_size,
                              hipStream_t stream) {
    const float* feat_user_d1 = (const float*)d_in[0];
    const float* feat_user_d2 = (const float*)d_in[1];
    const float* feat_d1      = (const float*)d_in[2];
    const float* feat_d2      = (const float*)d_in[3];
    const float* W_i2u_d1 = (const float*)d_in[4];
    const float* b_i2u_d1 = (const float*)d_in[5];
    const float* W_i2u_d2 = (const float*)d_in[6];
    const float* b_i2u_d2 = (const float*)d_in[7];
    const float* W_u2i_d1 = (const float*)d_in[8];
    const float* b_u2i_d1 = (const float*)d_in[9];
    const float* W_u2i_d2 = (const float*)d_in[10];
    const float* b_u2i_d2 = (const float*)d_in[11];
    const int* src_i2u_d1 = (const int*)d_in[12];
    const int* dst_i2u_d1 = (const int*)d_in[13];
    const int* src_i2u_d2 = (const int*)d_in[14];
    const int* dst_i2u_d2 = (const int*)d_in[15];
    const int* src_u2i_d1 = (const int*)d_in[16];
    const int* dst_u2i_d1 = (const int*)d_in[17];
    const int* src_u2i_d2 = (const int*)d_in[18];
    const int* dst_u2i_d2 = (const int*)d_in[19];

    float* out = (float*)d_out;

    // ws (ints): deg 8N | offs 4(N+1) | cursor 4N | csr 4E | part(+pad) 256 | bf16 feats
    int* deg    = (int*)d_ws;
    const float* rinv = (const float*)d_ws;
    int* offs   = deg + 8 * (size_t)N_NODES;
    int* cursor = offs + 4 * (size_t)(N_NODES + 1);
    int* csr    = cursor + 4 * (size_t)N_NODES;
    int* part   = csr + 4 * (size_t)N_EDGES;
    unsigned short* bf = (unsigned short*)(part + 256);
    size_t need_bf = ((char*)(bf + 4 * (size_t)N_NODES * DIM)) - (char*)d_ws;
    const bool use_bf16 = (ws_size >= need_bf);

    hipMemsetAsync(deg, 0, 8 * (size_t)N_NODES * sizeof(int), stream);

    IdxPtrs8 cidx = {{src_i2u_d1, dst_i2u_d1, src_i2u_d2, dst_i2u_d2,
                      src_u2i_d1, dst_u2i_d1, src_u2i_d2, dst_u2i_d2}};
    count_all<<<dim3((N_EDGES / 4 + 255) / 256, 8), 256, 0, stream>>>(cidx, deg);

    scan_partial<<<dim3(NB, 4), 256, 0, stream>>>(deg, part);
    scan_base<<<1, 256, 0, stream>>>(part);
    scan_write<<<dim3(NB, 4), 256, 0, stream>>>(deg, part, offs, cursor);

    SrcDst4 sd = {{src_i2u_d1, src_i2u_d2, src_u2i_d1, src_u2i_d2},
                  {dst_i2u_d1, dst_i2u_d2, dst_u2i_d1, dst_u2i_d2}};
    fill_all<<<dim3((N_EDGES / 4 + 1023) / 1024, 4), 256, 0, stream>>>(sd, cursor, csr);

    FeatPtrs fp = {{feat_d1, feat_d2, feat_user_d1, feat_user_d2}};
    if (use_bf16) {
        to_bf16<<<dim3((N_NODES * DIM / 8 + 255) / 256, 4), 256, 0, stream>>>(fp, deg, bf);
        gather_bf16<<<dim3((N_NODES + 3) / 4, 4), 256, 0, stream>>>(bf, rinv, csr, offs, out);
    } else {
        gather_f32<<<dim3((N_NODES + 3) / 4, 4), 256, 0, stream>>>(fp, deg, csr, offs, out);
    }

    GemmArgs ga = {{W_i2u_d1, W_i2u_d2, W_u2i_d1, W_u2i_d2},
                   {b_i2u_d1, b_i2u_d2, b_u2i_d1, b_u2i_d2}};
    gemm_all<<<dim3((N_NODES + 31) / 32, 3), 256, 0, stream>>>(ga, out);
}